// Round 1
// baseline (186.692 us; speedup 1.0000x reference)
//
#include <hip/hip_runtime.h>

// FilteredLReLU: up2(17-tap) -> *2 -> lrelu(0.01) -> down2(17-tap)
// x: [8,256,32768] f32, filters 17 taps f32, out [8,256,32768] f32.
//
// Polyphase fusion:
//   y_even[m] = sum_{j=0..8} up[2j]   * x[m-4+j]     (y[2m])
//   y_odd [m] = sum_{j=0..7} up[2j+1] * x[m-3+j]     (y[2m+1])
//   (UP gain of 2 folded into up taps)
//   ge[m] = lrelu(y_even[m]) for m in [0,T) else 0   (dn conv zero-pads y!)
//   go[m] = lrelu(y_odd [m]) for m in [0,T) else 0
//   z[t]  = sum_{j=0..8} dn[2j]*ge[t-4+j] + sum_{j=0..7} dn[2j+1]*go[t-4+j]

#define T_LEN   32768
#define TILE    1024
#define NTILES  (T_LEN / TILE)   // 32
#define SX_N    (TILE + 16)      // 1040: x[t0-8 .. t0+TILE+7]
#define NGE     (TILE + 8)       // 1032: m in [t0-4 .. t0+TILE+3]

__device__ __forceinline__ float lrelu(float v) {
    return v >= 0.0f ? v : 0.01f * v;
}

__global__ __launch_bounds__(256) void flrelu_fused(
    const float* __restrict__ x,
    const float* __restrict__ up,
    const float* __restrict__ dn,
    float* __restrict__ out)
{
    __shared__ __align__(16) float sx[SX_N];
    __shared__ __align__(16) float sge[NGE];
    __shared__ __align__(16) float sgo[NGE];

    const int tid  = threadIdx.x;
    const int row  = blockIdx.x >> 5;            // / NTILES
    const int tile = blockIdx.x & (NTILES - 1);
    const int t0   = tile * TILE;
    const float* __restrict__ xrow = x + (size_t)row * T_LEN;
    float* __restrict__ orow       = out + (size_t)row * T_LEN;

    // Filters into registers (constant indices -> uniform scalar loads).
    float fe[9], fo[8], de[9], dd[8];
    #pragma unroll
    for (int j = 0; j < 9; ++j) { fe[j] = 2.0f * up[2 * j]; de[j] = dn[2 * j]; }
    #pragma unroll
    for (int j = 0; j < 8; ++j) { fo[j] = 2.0f * up[2 * j + 1]; dd[j] = dn[2 * j + 1]; }

    // ---- stage 1: global -> LDS (x tile + 8-float halo each side) ----
    if (tile > 0 && tile < NTILES - 1) {
        // interior: fully in-range, 32B-aligned -> float4 loads
        const float4* src = reinterpret_cast<const float4*>(xrow + t0 - 8);
        float4* dst = reinterpret_cast<float4*>(sx);
        #pragma unroll
        for (int it = 0; it < 2; ++it) {
            int i4 = tid + it * 256;
            if (i4 < SX_N / 4) dst[i4] = src[i4];
        }
    } else {
        #pragma unroll
        for (int it = 0; it < 5; ++it) {
            int i = tid + it * 256;
            if (i < SX_N) {
                int g = t0 - 8 + i;
                sx[i] = (g >= 0 && g < T_LEN) ? xrow[g] : 0.0f;
            }
        }
    }
    __syncthreads();

    // ---- stage 2: polyphase upsample + leaky relu -> LDS ----
    #pragma unroll
    for (int it = 0; it < 2; ++it) {
        int mi = (tid + it * 256) * 4;           // 258 groups of 4 -> 1032
        if (mi < NGE) {
            float4 a = *reinterpret_cast<const float4*>(&sx[mi]);
            float4 b = *reinterpret_cast<const float4*>(&sx[mi + 4]);
            float4 c = *reinterpret_cast<const float4*>(&sx[mi + 8]);
            float w[12];
            w[0] = a.x; w[1] = a.y; w[2]  = a.z; w[3]  = a.w;
            w[4] = b.x; w[5] = b.y; w[6]  = b.z; w[7]  = b.w;
            w[8] = c.x; w[9] = c.y; w[10] = c.z; w[11] = c.w;
            float ge_[4], go_[4];
            #pragma unroll
            for (int r = 0; r < 4; ++r) {
                float ae = 0.0f, ao = 0.0f;
                #pragma unroll
                for (int j = 0; j < 9; ++j) ae = fmaf(fe[j], w[r + j], ae);
                #pragma unroll
                for (int j = 0; j < 8; ++j) ao = fmaf(fo[j], w[r + 1 + j], ao);
                int m = t0 - 4 + mi + r;
                bool valid = (m >= 0) && (m < T_LEN);
                ge_[r] = valid ? lrelu(ae) : 0.0f;
                go_[r] = valid ? lrelu(ao) : 0.0f;
            }
            *reinterpret_cast<float4*>(&sge[mi]) =
                make_float4(ge_[0], ge_[1], ge_[2], ge_[3]);
            *reinterpret_cast<float4*>(&sgo[mi]) =
                make_float4(go_[0], go_[1], go_[2], go_[3]);
        }
    }
    __syncthreads();

    // ---- stage 3: downsample (stride 2) -> global ----
    {
        const int ti = tid * 4;                  // 4 consecutive outputs
        float4 a = *reinterpret_cast<const float4*>(&sge[ti]);
        float4 b = *reinterpret_cast<const float4*>(&sge[ti + 4]);
        float4 c = *reinterpret_cast<const float4*>(&sge[ti + 8]);
        float4 p = *reinterpret_cast<const float4*>(&sgo[ti]);
        float4 q = *reinterpret_cast<const float4*>(&sgo[ti + 4]);
        float4 s = *reinterpret_cast<const float4*>(&sgo[ti + 8]);
        float e[12] = {a.x, a.y, a.z, a.w, b.x, b.y, b.z, b.w, c.x, c.y, c.z, c.w};
        float o[12] = {p.x, p.y, p.z, p.w, q.x, q.y, q.z, q.w, s.x, s.y, s.z, s.w};
        float z[4];
        #pragma unroll
        for (int r = 0; r < 4; ++r) {
            float acc = 0.0f;
            #pragma unroll
            for (int j = 0; j < 9; ++j) acc = fmaf(de[j], e[r + j], acc);
            #pragma unroll
            for (int j = 0; j < 8; ++j) acc = fmaf(dd[j], o[r + j], acc);
            z[r] = acc;
        }
        *reinterpret_cast<float4*>(&orow[t0 + ti]) =
            make_float4(z[0], z[1], z[2], z[3]);
    }
}

extern "C" void kernel_launch(void* const* d_in, const int* in_sizes, int n_in,
                              void* d_out, int out_size, void* d_ws, size_t ws_size,
                              hipStream_t stream) {
    const float* x  = (const float*)d_in[0];
    const float* up = (const float*)d_in[1];
    const float* dn = (const float*)d_in[2];
    float* out      = (float*)d_out;

    const int rows = in_sizes[0] / T_LEN;        // 8 * 256 = 2048
    dim3 grid(rows * NTILES);                    // 65536 blocks
    flrelu_fused<<<grid, 256, 0, stream>>>(x, up, dn, out);
}

// Round 2
// 181.711 us; speedup vs baseline: 1.0274x; 1.0274x over previous
//
#include <hip/hip_runtime.h>

// FilteredLReLU: up2(17-tap) -> *2 -> lrelu(0.01) -> down2(17-tap), fused.
// LDS-free streaming version: each thread produces 8 consecutive outputs
// entirely in registers; x halo re-read served by L1/L2/L3 (input fits L3).
//
// Polyphase math (UP gain folded into fe/fo):
//   ge[m] = lrelu( sum_{j=0..8} fe[j]*x[m-4+j] )   if 0<=m<T else 0
//   go[m] = lrelu( sum_{j=0..7} fo[j]*x[m-3+j] )   if 0<=m<T else 0
//   z[t]  = sum_{j=0..8} de[j]*ge[t-4+j] + sum_{j=0..7} dd[j]*go[t-4+j]

#define T_LEN 32768
#define R_OUT 8
#define TPR   (T_LEN / R_OUT)   // 4096 threads per row

__device__ __forceinline__ float lrelu(float v) {
    return v >= 0.0f ? v : 0.01f * v;
}

template <bool FAST>
__device__ __forceinline__ void compute8(
    const float* __restrict__ xrow, float* __restrict__ orow, int t,
    const float* fe, const float* fo, const float* de, const float* dd)
{
    float xv[R_OUT + 16];   // x[t-8 .. t+15]

    if (FAST) {
        const float4* xp = reinterpret_cast<const float4*>(xrow + t - 8);
        #pragma unroll
        for (int k = 0; k < (R_OUT + 16) / 4; ++k) {
            float4 v = xp[k];
            xv[4 * k + 0] = v.x; xv[4 * k + 1] = v.y;
            xv[4 * k + 2] = v.z; xv[4 * k + 3] = v.w;
        }
    } else {
        #pragma unroll
        for (int i = 0; i < R_OUT + 16; ++i) {
            int g = t - 8 + i;
            xv[i] = (g >= 0 && g < T_LEN) ? xrow[g] : 0.0f;
        }
    }

    float acc[R_OUT];
    #pragma unroll
    for (int r = 0; r < R_OUT; ++r) acc[r] = 0.0f;

    // even phase: ge[m], m = t-4+ml, ml = 0..R_OUT+7
    #pragma unroll
    for (int ml = 0; ml < R_OUT + 8; ++ml) {
        float ae = 0.0f;
        #pragma unroll
        for (int j = 0; j < 9; ++j) ae = fmaf(fe[j], xv[ml + j], ae);
        float g = lrelu(ae);
        if (!FAST) {
            int m = t - 4 + ml;
            if (m < 0 || m >= T_LEN) g = 0.0f;
        }
        #pragma unroll
        for (int r = 0; r < R_OUT; ++r)
            if (r >= ml - 8 && r <= ml)
                acc[r] = fmaf(de[ml - r], g, acc[r]);
    }

    // odd phase: go[m], m = t-4+ml, ml = 0..R_OUT+6
    #pragma unroll
    for (int ml = 0; ml < R_OUT + 7; ++ml) {
        float ao = 0.0f;
        #pragma unroll
        for (int j = 0; j < 8; ++j) ao = fmaf(fo[j], xv[ml + 1 + j], ao);
        float g = lrelu(ao);
        if (!FAST) {
            int m = t - 4 + ml;
            if (m < 0 || m >= T_LEN) g = 0.0f;
        }
        #pragma unroll
        for (int r = 0; r < R_OUT; ++r)
            if (r >= ml - 7 && r <= ml)
                acc[r] = fmaf(dd[ml - r], g, acc[r]);
    }

    float4* op = reinterpret_cast<float4*>(orow + t);
    op[0] = make_float4(acc[0], acc[1], acc[2], acc[3]);
    op[1] = make_float4(acc[4], acc[5], acc[6], acc[7]);
}

__global__ __launch_bounds__(256) void flrelu_stream(
    const float* __restrict__ x,
    const float* __restrict__ up,
    const float* __restrict__ dn,
    float* __restrict__ out)
{
    const int gid = blockIdx.x * 256 + threadIdx.x;
    const int row = gid >> 12;                 // / TPR
    const int t   = (gid & (TPR - 1)) * R_OUT;
    const float* __restrict__ xrow = x + (size_t)row * T_LEN;
    float* __restrict__ orow       = out + (size_t)row * T_LEN;

    // Filters: uniform read-only loads -> scalar regs. UP gain folded in.
    float fe[9], fo[8], de[9], dd[8];
    #pragma unroll
    for (int j = 0; j < 9; ++j) { fe[j] = 2.0f * up[2 * j]; de[j] = dn[2 * j]; }
    #pragma unroll
    for (int j = 0; j < 8; ++j) { fo[j] = 2.0f * up[2 * j + 1]; dd[j] = dn[2 * j + 1]; }

    if (t >= 8 && t <= T_LEN - R_OUT - 8) {
        compute8<true>(xrow, orow, t, fe, fo, de, dd);
    } else {
        compute8<false>(xrow, orow, t, fe, fo, de, dd);
    }
}

extern "C" void kernel_launch(void* const* d_in, const int* in_sizes, int n_in,
                              void* d_out, int out_size, void* d_ws, size_t ws_size,
                              hipStream_t stream) {
    const float* x  = (const float*)d_in[0];
    const float* up = (const float*)d_in[1];
    const float* dn = (const float*)d_in[2];
    float* out      = (float*)d_out;

    const int rows    = in_sizes[0] / T_LEN;         // 2048
    const int threads = rows * TPR;                  // 8.39M
    flrelu_stream<<<threads / 256, 256, 0, stream>>>(x, up, dn, out);
}